// Round 5
// baseline (545.597 us; speedup 1.0000x reference)
//
#include <hip/hip_runtime.h>
#include <hip/hip_bf16.h>

typedef __attribute__((ext_vector_type(8)))  short bf16x8_t;
typedef __attribute__((ext_vector_type(16))) float f32x16_t;
typedef __attribute__((ext_vector_type(4)))  float f32x4_t;

#define HN 10
#define BN 32768
#define DH 256
#define MT 128

#define HE   65536      // elems per (arr,head) weight matrix
#define ARRE 655360     // elems per layer-array (10 heads)

// LDS: abuf 64KB + s5 1KB
#define OFF_ABUF  0
#define OFF_S5    65536
#define SMEM_BYTES 66560

#define MFMA32 __builtin_amdgcn_mfma_f32_32x32x16_bf16

__device__ __forceinline__ unsigned swzoff(int row, int colb) {
  // [128][256] bf16 row-major, 512B/row; XOR row bits into byte bits 4-7
  return (unsigned)(row * 512 + (colb ^ ((row & 15) << 4)));
}

__device__ __forceinline__ unsigned short f2bf(float v) {
  __hip_bfloat16 hb = __float2bfloat16(v);
  return *reinterpret_cast<unsigned short*>(&hb);
}

// ---------------- prep kernels ----------------
struct WPtrs { const float* w[5]; };

extern "C" __global__ void pack_big(WPtrs p, unsigned short* __restrict__ dst)
{
  int g = blockIdx.x * blockDim.x + threadIdx.x;  // 409600
  if (g >= 5 * HN * 16 * 8 * 64) return;
  int lane = g & 63; int t = g >> 6;
  int nt = t & 7; t >>= 3;
  int ks = t & 15; t >>= 4;
  int h = t % HN;
  int a = t / HN;
  const float* src = p.w[a] + (size_t)h * 65536
                   + (nt * 32 + (lane & 31)) * 256 + ks * 16 + (lane >> 5) * 8;
  unsigned short* d = dst + (size_t)a * ARRE + (size_t)h * HE
                    + ((ks * 8 + nt) * 64 + lane) * 8;
  #pragma unroll
  for (int j = 0; j < 8; ++j) d[j] = f2bf(src[j]);
}

extern "C" __global__ void pack_w5(const float* __restrict__ w51, const float* __restrict__ w52,
                                   unsigned short* __restrict__ dst)
{
  int g = blockIdx.x * blockDim.x + threadIdx.x;  // 20480
  if (g >= 2 * HN * 16 * 64) return;
  int lane = g & 63; int t = g >> 6;
  int ks = t & 15; t >>= 4;
  int h = t % HN;
  int br = t / HN;
  const float* w = br ? w52 : w51;   // (10,2,256)
  int col = lane & 31;
  int k = ks * 16 + (lane >> 5) * 8;
  unsigned short* d = dst + ((size_t)(br * HN + h) * 16 + ks) * 512 + lane * 8;
  #pragma unroll
  for (int j = 0; j < 8; ++j) {
    float v = (col < 2) ? w[(size_t)h * 512 + col * 256 + k + j] : 0.f;
    d[j] = f2bf(v);
  }
}

// W1 (10,256,4) -> padded K=16 b-frags: [h][ntile(8)][lane(64)][8]
extern "C" __global__ void pack_w1(const float* __restrict__ w1, unsigned short* __restrict__ dst)
{
  int g = blockIdx.x * blockDim.x + threadIdx.x;  // 5120
  if (g >= HN * 8 * 64) return;
  int lane = g & 63; int t = g >> 6;
  int nt = t & 7;
  int h = t >> 3;
  int col = nt * 32 + (lane & 31);
  unsigned short* d = dst + (size_t)h * 4096 + ((size_t)nt * 64 + lane) * 8;
  #pragma unroll
  for (int j = 0; j < 8; ++j) {
    int k = (lane >> 5) * 8 + j;
    float v = (k < 4) ? w1[(size_t)h * 1024 + col * 4 + k] : 0.f;
    d[j] = f2bf(v);
  }
}

// ---------------- main kernel ----------------

// C-tile (relu+bf16) -> swizzled abuf
__device__ __forceinline__ void write_act(char* abuf, const f32x16_t acc[2][4],
                                          int lane, int wm, int wn)
{
  const int r31 = lane & 31, hi = lane >> 5;
  #pragma unroll
  for (int mt = 0; mt < 2; ++mt) {
    #pragma unroll
    for (int nt = 0; nt < 4; ++nt) {
      int colb = (wn * 128 + nt * 32 + r31) * 2;
      #pragma unroll
      for (int r = 0; r < 16; ++r) {
        int row = wm * 64 + mt * 32 + (r & 3) + 8 * (r >> 2) + 4 * hi;
        *(unsigned short*)(abuf + swzoff(row, colb)) = f2bf(fmaxf(acc[mt][nt][r], 0.f));
      }
    }
  }
}

// In-place 128x256 @ 256x256 GEMM + bias + relu. Wave tile 64 rows x 128 cols
// (wm in [0,2), wn in [0,2)). B streamed from L2, 3-slot rotation, depth-2 prefetch.
__device__ __forceinline__ void gemm_ip(char* abuf,
                                        const unsigned short* __restrict__ wl,
                                        const float* __restrict__ bias,
                                        int lane, int wm, int wn)
{
  const int r31 = lane & 31, hi = lane >> 5;
  f32x16_t acc[2][4];
  #pragma unroll
  for (int nt = 0; nt < 4; ++nt) {
    float bv = bias[wn * 128 + nt * 32 + r31];
    #pragma unroll
    for (int i = 0; i < 16; ++i) { acc[0][nt][i] = bv; acc[1][nt][i] = bv; }
  }

  const char* wb = (const char*)wl + wn * 4096 + (size_t)lane * 16;
  bf16x8_t b[3][4];
  #pragma unroll
  for (int s = 0; s < 2; ++s)
    #pragma unroll
    for (int nt = 0; nt < 4; ++nt)
      b[s][nt] = *(const bf16x8_t*)(wb + s * 8192 + nt * 1024);

  #pragma unroll
  for (int ks = 0; ks < 16; ++ks) {
    if (ks < 14) {
      #pragma unroll
      for (int nt = 0; nt < 4; ++nt)
        b[(ks + 2) % 3][nt] = *(const bf16x8_t*)(wb + (ks + 2) * 8192 + nt * 1024);
    }
    bf16x8_t a0 = *(const bf16x8_t*)(abuf + swzoff(wm * 64 + r31,      ks * 32 + hi * 16));
    bf16x8_t a1 = *(const bf16x8_t*)(abuf + swzoff(wm * 64 + 32 + r31, ks * 32 + hi * 16));
    #pragma unroll
    for (int nt = 0; nt < 4; ++nt) {
      acc[0][nt] = MFMA32(a0, b[ks % 3][nt], acc[0][nt], 0, 0, 0);
      acc[1][nt] = MFMA32(a1, b[ks % 3][nt], acc[1][nt], 0, 0, 0);
    }
  }
  __syncthreads();   // all A-reads landed in acc -> in-place overwrite safe
  write_act(abuf, acc, lane, wm, wn);
  __syncthreads();
}

extern "C" __global__ __launch_bounds__(256, 2)
void abnet_main(const float* __restrict__ x,
                const float* __restrict__ b1,
                const float* __restrict__ b2, const float* __restrict__ b31,
                const float* __restrict__ b32, const float* __restrict__ b41,
                const float* __restrict__ b42, const float* __restrict__ b51,
                const float* __restrict__ b52,
                const unsigned short* __restrict__ wpk,
                const unsigned short* __restrict__ w5pk,
                const unsigned short* __restrict__ w1pk,
                float* __restrict__ ws51, float* __restrict__ ws52)
{
  extern __shared__ char smem[];
  char*  abuf = smem + OFF_ABUF;
  float* s5   = (float*)(smem + OFF_S5);

  const int tid  = threadIdx.x;
  const int lane = tid & 63, wave = tid >> 6;
  const int wm = wave >> 1, wn = wave & 1;
  // XCD-chunked swizzle: 640 consecutive logical blocks per XCD -> same (h,br)
  // weight set stays resident in that XCD's L2 (~1MB per XCD).
  const int L  = (blockIdx.x & 7) * 640 + (blockIdx.x >> 3);
  const int rt = L & 255;
  const int hb = L >> 8;                 // 0..19
  const int h  = hb >> 1, br = hb & 1;
  const int row0 = rt * MT;

  const int r31 = lane & 31, hi = lane >> 5;

  // ---- layer 1 via padded-K MFMA ----
  {
    const float* b1g = b1 + (size_t)h * 256;
    f32x16_t acc[2][4];
    #pragma unroll
    for (int nt = 0; nt < 4; ++nt) {
      float bv = b1g[wn * 128 + nt * 32 + r31];
      #pragma unroll
      for (int i = 0; i < 16; ++i) { acc[0][nt][i] = bv; acc[1][nt][i] = bv; }
    }
    const char* w1b = (const char*)(w1pk + (size_t)h * 4096) + wn * 4096 + (size_t)lane * 16;
    bf16x8_t bfr[4];
    #pragma unroll
    for (int nt = 0; nt < 4; ++nt) bfr[nt] = *(const bf16x8_t*)(w1b + nt * 1024);
    #pragma unroll
    for (int mt = 0; mt < 2; ++mt) {
      int row = row0 + wm * 64 + mt * 32 + r31;
      f32x4_t xv = *(const f32x4_t*)(x + (size_t)row * 4);
      bf16x8_t af;
      #pragma unroll
      for (int j = 0; j < 8; ++j)
        af[j] = (hi == 0 && j < 4) ? (short)f2bf(xv[j]) : (short)0;
      #pragma unroll
      for (int nt = 0; nt < 4; ++nt)
        acc[mt][nt] = MFMA32(af, bfr[nt], acc[mt][nt], 0, 0, 0);
    }
    __syncthreads();
    write_act(abuf, acc, lane, wm, wn);
    __syncthreads();
  }

  // ---- three 256x256 layers, in place ----
  gemm_ip(abuf, wpk + (size_t)h * HE,                           b2  + (size_t)h * 256, lane, wm, wn); // x2
  gemm_ip(abuf, wpk + (size_t)(1 + br) * ARRE + (size_t)h * HE, (br ? b32 : b31) + (size_t)h * 256, lane, wm, wn); // x3b
  gemm_ip(abuf, wpk + (size_t)(3 + br) * ARRE + (size_t)h * HE, (br ? b42 : b41) + (size_t)h * 256, lane, wm, wn); // x4b

  // ---- final 256->2: wave = m-tile, full K per wave ----
  {
    const unsigned short* w5 = w5pk + (size_t)(br * HN + h) * 8192;
    const float* b5g = (br ? b52 : b51) + (size_t)h * 2;
    const int mt = wave;
    float bv = (r31 < 2) ? b5g[r31] : 0.f;
    f32x16_t acc;
    #pragma unroll
    for (int i = 0; i < 16; ++i) acc[i] = bv;
    #pragma unroll
    for (int ks = 0; ks < 16; ++ks) {
      bf16x8_t a = *(const bf16x8_t*)(abuf + swzoff(mt * 32 + r31, ks * 32 + hi * 16));
      bf16x8_t b = *(const bf16x8_t*)(w5 + (size_t)(ks * 64 + lane) * 8);
      acc = MFMA32(a, b, acc, 0, 0, 0);
    }
    if (r31 < 2) {
      #pragma unroll
      for (int r = 0; r < 16; ++r) {
        int row = mt * 32 + (r & 3) + 8 * (r >> 2) + 4 * hi;
        s5[row * 2 + r31] = acc[r];
      }
    }
  }
  __syncthreads();

  // ---- write raw final outputs ----
  if (tid < 256) {
    int row = tid >> 1, c = tid & 1;
    float* wsout = br ? ws52 : ws51;
    wsout[((size_t)h * BN + row0 + row) * 2 + c] = s5[row * 2 + c];
  }
}

// ---------------- epilogue: CBF + softmax-weighted head combine ----------------
extern "C" __global__ __launch_bounds__(256)
void abnet_epi(const float* __restrict__ x, const float* __restrict__ wt,
               const float* __restrict__ mean, const float* __restrict__ stdv,
               const float* __restrict__ mlab, const float* __restrict__ slab,
               const float* __restrict__ ws51, const float* __restrict__ ws52,
               float* __restrict__ out)
{
  const int row = blockIdx.x * 256 + threadIdx.x;
  f32x4_t xr = *(const f32x4_t*)(x + (size_t)row * 4);
  float t1  = xr[0] * stdv[0] + mean[0];
  float w1v = xr[1] * stdv[1] + mean[1];
  float t2  = xr[2] * stdv[2] + mean[2];
  float w2v = xr[3] * stdv[3] + mean[3];
  float s1, c1, s2, c2;
  sincosf(t1, &s1, &c1);
  sincosf(t2, &s2, &c2);
  float px = 3.f * c1 + 3.f * c2;                // OBS_X = 0
  float py = 3.f * s1 + 3.f * s2 - 7.f;          // OBS_Y = 7
  float vx = -3.f * s1 * w1v - 3.f * s2 * w2v;
  float vy =  3.f * c1 * w1v + 3.f * c2 * w2v;
  float e_bar  = px * px + py * py - 16.f;       // R^2
  float e_bdot = 2.f * (px * vx + py * vy);
  float e_lf2b = 2.f * vx * vx + 2.f * vy * vy
               + 2.f * px * (-3.f * c1 * w1v * w1v - 3.f * c2 * w2v * w2v)
               + 2.f * py * (-3.f * s1 * w1v * w1v - 3.f * s2 * w2v * w2v);
  float e_g1 = 6.f * (px * s1 - py * c1);
  float e_g2 = 6.f * (px * s2 - py * c2);
  float e_ggi = 1.f / (e_g1 * e_g1 + e_g2 * e_g2);

  float m = wt[0];
  for (int i = 1; i < HN; ++i) m = fmaxf(m, wt[i]);
  float s = 0.f;
  for (int i = 0; i < HN; ++i) s += __expf(wt[i] - m);
  float sm_inv = 1.f / s;
  float ml0 = mlab[0], ml1 = mlab[1];
  float isl0 = 1.f / slab[0], isl1 = 1.f / slab[1];

  float a0r = 4.f / (1.f + __expf(-ws52[(size_t)row * 2 + 0]));   // head 0, col 0
  float accu0 = 0.f, accu1 = 0.f;
  for (int h = 0; h < HN; ++h) {
    float u1 = -ws51[((size_t)h * BN + row) * 2 + 0];
    float u2 = -ws51[((size_t)h * BN + row) * 2 + 1];
    float bi = 4.f / (1.f + __expf(-ws52[((size_t)h * BN + row) * 2 + 1]));
    float hv   = e_lf2b + (a0r + bi) * e_bdot + a0r * bi * e_bar;
    float viol = u1 * e_g1 + u2 * e_g2 - hv;
    float lam  = fmaxf(viol, 0.f) * e_ggi;
    float uu1 = u1 - lam * e_g1;
    float uu2 = u2 - lam * e_g2;
    float whv = __expf(wt[h] - m) * sm_inv;
    accu0 += whv * (uu1 - ml0) * isl0;
    accu1 += whv * (uu2 - ml1) * isl1;
  }
  float2 o; o.x = accu0; o.y = accu1;
  *(float2*)(out + (size_t)row * 2) = o;
}

// ---------------- launch ----------------
extern "C" void kernel_launch(void* const* d_in, const int* in_sizes, int n_in,
                              void* d_out, int out_size, void* d_ws, size_t ws_size,
                              hipStream_t stream)
{
  const float* x    = (const float*)d_in[0];
  const float* wt   = (const float*)d_in[2];
  const float* mean = (const float*)d_in[3];
  const float* stdv = (const float*)d_in[4];
  const float* mlab = (const float*)d_in[5];
  const float* slab = (const float*)d_in[6];
  const float* W1   = (const float*)d_in[7];
  const float* b1   = (const float*)d_in[8];
  WPtrs wp;
  wp.w[0] = (const float*)d_in[9];   // W2
  wp.w[1] = (const float*)d_in[11];  // W31
  wp.w[2] = (const float*)d_in[13];  // W32
  wp.w[3] = (const float*)d_in[15];  // W41
  wp.w[4] = (const float*)d_in[17];  // W42
  const float* b2  = (const float*)d_in[10];
  const float* b31 = (const float*)d_in[12];
  const float* b32 = (const float*)d_in[14];
  const float* b41 = (const float*)d_in[16];
  const float* b42 = (const float*)d_in[18];
  const float* W51 = (const float*)d_in[19];
  const float* b51 = (const float*)d_in[20];
  const float* W52 = (const float*)d_in[21];
  const float* b52 = (const float*)d_in[22];

  char* wsb = (char*)d_ws;
  unsigned short* wpk  = (unsigned short*)wsb;                       // 6,553,600 B
  unsigned short* w5pk = (unsigned short*)(wsb + 6553600);           //   327,680 B
  unsigned short* w1pk = (unsigned short*)(wsb + 6881280);           //    81,920 B
  float* ws51 = (float*)(wsb + 6963200);                             // 2,621,440 B
  float* ws52 = (float*)(wsb + 9584640);                             // 2,621,440 B

  hipLaunchKernelGGL(pack_big, dim3(1600), dim3(256), 0, stream, wp, wpk);
  hipLaunchKernelGGL(pack_w5,  dim3(80),   dim3(256), 0, stream, W51, W52, w5pk);
  hipLaunchKernelGGL(pack_w1,  dim3(20),   dim3(256), 0, stream, W1, w1pk);

  (void)hipFuncSetAttribute(reinterpret_cast<const void*>(abnet_main),
                            hipFuncAttributeMaxDynamicSharedMemorySize, SMEM_BYTES);
  hipLaunchKernelGGL(abnet_main, dim3(256 * HN * 2), dim3(256), SMEM_BYTES, stream,
                     x, b1, b2, b31, b32, b41, b42, b51, b52,
                     wpk, w5pk, w1pk, ws51, ws52);
  hipLaunchKernelGGL(abnet_epi, dim3(BN / 256), dim3(256), 0, stream,
                     x, wt, mean, stdv, mlab, slab, ws51, ws52, (float*)d_out);
}

// Round 6
// 322.791 us; speedup vs baseline: 1.6902x; 1.6902x over previous
//
#include <hip/hip_runtime.h>
#include <hip/hip_bf16.h>

typedef __attribute__((ext_vector_type(8)))  short bf16x8_t;
typedef __attribute__((ext_vector_type(16))) float f32x16_t;
typedef __attribute__((ext_vector_type(4)))  float f32x4_t;

#define HN 10
#define BN 32768
#define DH 256
#define MT 128

#define HE   65536      // elems per (arr,head) weight matrix
#define ARRE 655360     // elems per layer-array (10 heads)

// LDS: abuf 64KB + s5 1KB
#define OFF_ABUF  0
#define OFF_S5    65536
#define SMEM_BYTES 66560

#define MFMA32 __builtin_amdgcn_mfma_f32_32x32x16_bf16

__device__ __forceinline__ unsigned swzoff(int row, int colb) {
  // [128][256] bf16 row-major, 512B/row; XOR row bits into byte bits 4-7
  return (unsigned)(row * 512 + (colb ^ ((row & 15) << 4)));
}

__device__ __forceinline__ unsigned short f2bf(float v) {
  __hip_bfloat16 hb = __float2bfloat16(v);
  return *reinterpret_cast<unsigned short*>(&hb);
}

// ---------------- prep kernels (layouts verified R1-R5) ----------------
struct WPtrs { const float* w[5]; };

extern "C" __global__ void pack_big(WPtrs p, unsigned short* __restrict__ dst)
{
  int g = blockIdx.x * blockDim.x + threadIdx.x;  // 409600
  if (g >= 5 * HN * 16 * 8 * 64) return;
  int lane = g & 63; int t = g >> 6;
  int nt = t & 7; t >>= 3;
  int ks = t & 15; t >>= 4;
  int h = t % HN;
  int a = t / HN;
  const float* src = p.w[a] + (size_t)h * 65536
                   + (nt * 32 + (lane & 31)) * 256 + ks * 16 + (lane >> 5) * 8;
  unsigned short* d = dst + (size_t)a * ARRE + (size_t)h * HE
                    + ((ks * 8 + nt) * 64 + lane) * 8;
  #pragma unroll
  for (int j = 0; j < 8; ++j) d[j] = f2bf(src[j]);
}

extern "C" __global__ void pack_w5(const float* __restrict__ w51, const float* __restrict__ w52,
                                   unsigned short* __restrict__ dst)
{
  int g = blockIdx.x * blockDim.x + threadIdx.x;  // 20480
  if (g >= 2 * HN * 16 * 64) return;
  int lane = g & 63; int t = g >> 6;
  int ks = t & 15; t >>= 4;
  int h = t % HN;
  int br = t / HN;
  const float* w = br ? w52 : w51;   // (10,2,256)
  int col = lane & 31;
  int k = ks * 16 + (lane >> 5) * 8;
  unsigned short* d = dst + ((size_t)(br * HN + h) * 16 + ks) * 512 + lane * 8;
  #pragma unroll
  for (int j = 0; j < 8; ++j) {
    float v = (col < 2) ? w[(size_t)h * 512 + col * 256 + k + j] : 0.f;
    d[j] = f2bf(v);
  }
}

// W1 (10,256,4) -> padded K=16 b-frags: [h][ntile(8)][lane(64)][8]
extern "C" __global__ void pack_w1(const float* __restrict__ w1, unsigned short* __restrict__ dst)
{
  int g = blockIdx.x * blockDim.x + threadIdx.x;  // 5120
  if (g >= HN * 8 * 64) return;
  int lane = g & 63; int t = g >> 6;
  int nt = t & 7;
  int h = t >> 3;
  int col = nt * 32 + (lane & 31);
  unsigned short* d = dst + (size_t)h * 4096 + ((size_t)nt * 64 + lane) * 8;
  #pragma unroll
  for (int j = 0; j < 8; ++j) {
    int k = (lane >> 5) * 8 + j;
    float v = (k < 4) ? w1[(size_t)h * 1024 + col * 4 + k] : 0.f;
    d[j] = f2bf(v);
  }
}

// ---------------- main kernel ----------------

// C-tile (relu+bf16) -> swizzled abuf, wave tile 64x64
__device__ __forceinline__ void write_act(char* abuf, const f32x16_t acc[2][2],
                                          int lane, int wm, int wn)
{
  const int r31 = lane & 31, hi = lane >> 5;
  #pragma unroll
  for (int mt = 0; mt < 2; ++mt) {
    #pragma unroll
    for (int nt = 0; nt < 2; ++nt) {
      int colb = (wn * 64 + nt * 32 + r31) * 2;
      #pragma unroll
      for (int r = 0; r < 16; ++r) {
        int row = wm * 64 + mt * 32 + (r & 3) + 8 * (r >> 2) + 4 * hi;
        *(unsigned short*)(abuf + swzoff(row, colb)) = f2bf(fmaxf(acc[mt][nt][r], 0.f));
      }
    }
  }
}

// In-place 128x256 @ 256x256 GEMM + bias + relu. Wave tile 64 rows x 64 cols
// (wm in [0,2), wn in [0,4)). B streamed from L2, depth-2 rotation.
// acc = 64 VGPR; total live ~110 -> fits 128-VGPR budget, no spills.
__device__ __forceinline__ void gemm_ip(char* abuf,
                                        const unsigned short* __restrict__ wl,
                                        const float* __restrict__ bias,
                                        int lane, int wm, int wn)
{
  const int r31 = lane & 31, hi = lane >> 5;
  const float bv0 = bias[wn * 64 + r31];
  const float bv1 = bias[wn * 64 + 32 + r31];
  f32x16_t acc[2][2];
  #pragma unroll
  for (int i = 0; i < 16; ++i) {
    acc[0][0][i] = bv0; acc[0][1][i] = bv1;
    acc[1][0][i] = bv0; acc[1][1][i] = bv1;
  }

  // frag(ks,nt) at byte offset ((ks*8+nt)*64+lane)*16
  const char* wb = (const char*)wl + (wn * 2) * 1024 + (size_t)lane * 16;
  bf16x8_t c0 = *(const bf16x8_t*)(wb);
  bf16x8_t c1 = *(const bf16x8_t*)(wb + 1024);
  bf16x8_t n0 = *(const bf16x8_t*)(wb + 8192);
  bf16x8_t n1 = *(const bf16x8_t*)(wb + 8192 + 1024);

  #pragma unroll
  for (int ks = 0; ks < 16; ++ks) {
    bf16x8_t p0, p1;
    if (ks < 14) {
      p0 = *(const bf16x8_t*)(wb + (ks + 2) * 8192);
      p1 = *(const bf16x8_t*)(wb + (ks + 2) * 8192 + 1024);
    }
    bf16x8_t a0 = *(const bf16x8_t*)(abuf + swzoff(wm * 64 + r31,      ks * 32 + hi * 16));
    bf16x8_t a1 = *(const bf16x8_t*)(abuf + swzoff(wm * 64 + 32 + r31, ks * 32 + hi * 16));
    acc[0][0] = MFMA32(a0, c0, acc[0][0], 0, 0, 0);
    acc[0][1] = MFMA32(a0, c1, acc[0][1], 0, 0, 0);
    acc[1][0] = MFMA32(a1, c0, acc[1][0], 0, 0, 0);
    acc[1][1] = MFMA32(a1, c1, acc[1][1], 0, 0, 0);
    c0 = n0; c1 = n1; n0 = p0; n1 = p1;
  }
  __syncthreads();   // all A-reads landed in acc -> in-place overwrite safe
  write_act(abuf, acc, lane, wm, wn);
  __syncthreads();
}

extern "C" __global__ __launch_bounds__(512, 2)
void abnet_main(const float* __restrict__ x,
                const float* __restrict__ b1,
                const float* __restrict__ b2, const float* __restrict__ b31,
                const float* __restrict__ b32, const float* __restrict__ b41,
                const float* __restrict__ b42, const float* __restrict__ b51,
                const float* __restrict__ b52,
                const unsigned short* __restrict__ wpk,
                const unsigned short* __restrict__ w5pk,
                const unsigned short* __restrict__ w1pk,
                float* __restrict__ ws51, float* __restrict__ ws52)
{
  extern __shared__ char smem[];
  char*  abuf = smem + OFF_ABUF;
  float* s5   = (float*)(smem + OFF_S5);

  const int tid  = threadIdx.x;
  const int lane = tid & 63, wave = tid >> 6;
  const int wm = wave >> 2, wn = wave & 3;
  // XCD-chunked swizzle: 640 consecutive logical blocks per XCD -> the XCD's
  // 2.5 (h,br) weight sets (~1.2MB) stay resident in its private L2.
  const int L  = (blockIdx.x & 7) * 640 + (blockIdx.x >> 3);
  const int rt = L & 255;
  const int hb = L >> 8;                 // 0..19
  const int h  = hb >> 1, br = hb & 1;
  const int row0 = rt * MT;

  const int r31 = lane & 31, hi = lane >> 5;

  // ---- layer 1 via padded-K MFMA (K=4 padded to 16) ----
  {
    const float* b1g = b1 + (size_t)h * 256;
    const float bv0 = b1g[wn * 64 + r31];
    const float bv1 = b1g[wn * 64 + 32 + r31];
    f32x16_t acc[2][2];
    #pragma unroll
    for (int i = 0; i < 16; ++i) {
      acc[0][0][i] = bv0; acc[0][1][i] = bv1;
      acc[1][0][i] = bv0; acc[1][1][i] = bv1;
    }
    const char* w1b = (const char*)(w1pk + (size_t)h * 4096) + (wn * 2) * 1024 + (size_t)lane * 16;
    bf16x8_t bf0 = *(const bf16x8_t*)(w1b);
    bf16x8_t bf1 = *(const bf16x8_t*)(w1b + 1024);
    #pragma unroll
    for (int mt = 0; mt < 2; ++mt) {
      int row = row0 + wm * 64 + mt * 32 + r31;
      f32x4_t xv = *(const f32x4_t*)(x + (size_t)row * 4);
      bf16x8_t af;
      #pragma unroll
      for (int j = 0; j < 8; ++j)
        af[j] = (hi == 0 && j < 4) ? (short)f2bf(xv[j]) : (short)0;
      acc[mt][0] = MFMA32(af, bf0, acc[mt][0], 0, 0, 0);
      acc[mt][1] = MFMA32(af, bf1, acc[mt][1], 0, 0, 0);
    }
    __syncthreads();
    write_act(abuf, acc, lane, wm, wn);
    __syncthreads();
  }

  // ---- three 256x256 layers, in place ----
  gemm_ip(abuf, wpk + (size_t)h * HE,                           b2  + (size_t)h * 256, lane, wm, wn); // x2
  gemm_ip(abuf, wpk + (size_t)(1 + br) * ARRE + (size_t)h * HE, (br ? b32 : b31) + (size_t)h * 256, lane, wm, wn); // x3b
  gemm_ip(abuf, wpk + (size_t)(3 + br) * ARRE + (size_t)h * HE, (br ? b42 : b41) + (size_t)h * 256, lane, wm, wn); // x4b

  // ---- final 256->2: waves 0..3 each take a 32-row m-tile, full K ----
  if (wave < 4) {
    const unsigned short* w5 = w5pk + (size_t)(br * HN + h) * 8192;
    const float* b5g = (br ? b52 : b51) + (size_t)h * 2;
    const int mt = wave;
    float bv = (r31 < 2) ? b5g[r31] : 0.f;
    f32x16_t acc;
    #pragma unroll
    for (int i = 0; i < 16; ++i) acc[i] = bv;
    #pragma unroll
    for (int ks = 0; ks < 16; ++ks) {
      bf16x8_t a = *(const bf16x8_t*)(abuf + swzoff(mt * 32 + r31, ks * 32 + hi * 16));
      bf16x8_t b = *(const bf16x8_t*)(w5 + (size_t)(ks * 64 + lane) * 8);
      acc = MFMA32(a, b, acc, 0, 0, 0);
    }
    if (r31 < 2) {
      #pragma unroll
      for (int r = 0; r < 16; ++r) {
        int row = mt * 32 + (r & 3) + 8 * (r >> 2) + 4 * hi;
        s5[row * 2 + r31] = acc[r];
      }
    }
  }
  __syncthreads();

  // ---- write raw final outputs (activation applied in epilogue) ----
  if (tid < 256) {
    int row = tid >> 1, c = tid & 1;
    float* wsout = br ? ws52 : ws51;
    wsout[((size_t)h * BN + row0 + row) * 2 + c] = s5[row * 2 + c];
  }
}

// ---------------- epilogue: CBF + softmax-weighted head combine ----------------
extern "C" __global__ __launch_bounds__(256)
void abnet_epi(const float* __restrict__ x, const float* __restrict__ wt,
               const float* __restrict__ mean, const float* __restrict__ stdv,
               const float* __restrict__ mlab, const float* __restrict__ slab,
               const float* __restrict__ ws51, const float* __restrict__ ws52,
               float* __restrict__ out)
{
  const int row = blockIdx.x * 256 + threadIdx.x;
  f32x4_t xr = *(const f32x4_t*)(x + (size_t)row * 4);
  float t1  = xr[0] * stdv[0] + mean[0];
  float w1v = xr[1] * stdv[1] + mean[1];
  float t2  = xr[2] * stdv[2] + mean[2];
  float w2v = xr[3] * stdv[3] + mean[3];
  float s1, c1, s2, c2;
  sincosf(t1, &s1, &c1);
  sincosf(t2, &s2, &c2);
  float px = 3.f * c1 + 3.f * c2;                // OBS_X = 0
  float py = 3.f * s1 + 3.f * s2 - 7.f;          // OBS_Y = 7
  float vx = -3.f * s1 * w1v - 3.f * s2 * w2v;
  float vy =  3.f * c1 * w1v + 3.f * c2 * w2v;
  float e_bar  = px * px + py * py - 16.f;       // R^2
  float e_bdot = 2.f * (px * vx + py * vy);
  float e_lf2b = 2.f * vx * vx + 2.f * vy * vy
               + 2.f * px * (-3.f * c1 * w1v * w1v - 3.f * c2 * w2v * w2v)
               + 2.f * py * (-3.f * s1 * w1v * w1v - 3.f * s2 * w2v * w2v);
  float e_g1 = 6.f * (px * s1 - py * c1);
  float e_g2 = 6.f * (px * s2 - py * c2);
  float e_ggi = 1.f / (e_g1 * e_g1 + e_g2 * e_g2);

  float m = wt[0];
  for (int i = 1; i < HN; ++i) m = fmaxf(m, wt[i]);
  float s = 0.f;
  for (int i = 0; i < HN; ++i) s += __expf(wt[i] - m);
  float sm_inv = 1.f / s;
  float ml0 = mlab[0], ml1 = mlab[1];
  float isl0 = 1.f / slab[0], isl1 = 1.f / slab[1];

  float a0r = 4.f / (1.f + __expf(-ws52[(size_t)row * 2 + 0]));   // head 0, col 0
  float accu0 = 0.f, accu1 = 0.f;
  for (int h = 0; h < HN; ++h) {
    float u1 = -ws51[((size_t)h * BN + row) * 2 + 0];
    float u2 = -ws51[((size_t)h * BN + row) * 2 + 1];
    float bi = 4.f / (1.f + __expf(-ws52[((size_t)h * BN + row) * 2 + 1]));
    float hv   = e_lf2b + (a0r + bi) * e_bdot + a0r * bi * e_bar;
    float viol = u1 * e_g1 + u2 * e_g2 - hv;
    float lam  = fmaxf(viol, 0.f) * e_ggi;
    float uu1 = u1 - lam * e_g1;
    float uu2 = u2 - lam * e_g2;
    float whv = __expf(wt[h] - m) * sm_inv;
    accu0 += whv * (uu1 - ml0) * isl0;
    accu1 += whv * (uu1 * 0.f + uu2 - ml1) * isl1;
  }
  float2 o; o.x = accu0; o.y = accu1;
  *(float2*)(out + (size_t)row * 2) = o;
}

// ---------------- launch ----------------
extern "C" void kernel_launch(void* const* d_in, const int* in_sizes, int n_in,
                              void* d_out, int out_size, void* d_ws, size_t ws_size,
                              hipStream_t stream)
{
  const float* x    = (const float*)d_in[0];
  const float* wt   = (const float*)d_in[2];
  const float* mean = (const float*)d_in[3];
  const float* stdv = (const float*)d_in[4];
  const float* mlab = (const float*)d_in[5];
  const float* slab = (const float*)d_in[6];
  const float* W1   = (const float*)d_in[7];
  const float* b1   = (const float*)d_in[8];
  WPtrs wp;
  wp.w[0] = (const float*)d_in[9];   // W2
  wp.w[1] = (const float*)d_in[11];  // W31
  wp.w[2] = (const float*)d_in[13];  // W32
  wp.w[3] = (const float*)d_in[15];  // W41
  wp.w[4] = (const float*)d_in[17];  // W42
  const float* b2  = (const float*)d_in[10];
  const float* b31 = (const float*)d_in[12];
  const float* b32 = (const float*)d_in[14];
  const float* b41 = (const float*)d_in[16];
  const float* b42 = (const float*)d_in[18];
  const float* W51 = (const float*)d_in[19];
  const float* b51 = (const float*)d_in[20];
  const float* W52 = (const float*)d_in[21];
  const float* b52 = (const float*)d_in[22];

  char* wsb = (char*)d_ws;
  unsigned short* wpk  = (unsigned short*)wsb;                       // 6,553,600 B
  unsigned short* w5pk = (unsigned short*)(wsb + 6553600);           //   327,680 B
  unsigned short* w1pk = (unsigned short*)(wsb + 6881280);           //    81,920 B
  float* ws51 = (float*)(wsb + 6963200);                             // 2,621,440 B
  float* ws52 = (float*)(wsb + 9584640);                             // 2,621,440 B

  hipLaunchKernelGGL(pack_big, dim3(1600), dim3(256), 0, stream, wp, wpk);
  hipLaunchKernelGGL(pack_w5,  dim3(80),   dim3(256), 0, stream, W51, W52, w5pk);
  hipLaunchKernelGGL(pack_w1,  dim3(20),   dim3(256), 0, stream, W1, w1pk);

  (void)hipFuncSetAttribute(reinterpret_cast<const void*>(abnet_main),
                            hipFuncAttributeMaxDynamicSharedMemorySize, SMEM_BYTES);
  hipLaunchKernelGGL(abnet_main, dim3(256 * HN * 2), dim3(512), SMEM_BYTES, stream,
                     x, b1, b2, b31, b32, b41, b42, b51, b52,
                     wpk, w5pk, w1pk, ws51, ws52);
  hipLaunchKernelGGL(abnet_epi, dim3(BN / 256), dim3(256), 0, stream,
                     x, wt, mean, stdv, mlab, slab, ws51, ws52, (float*)d_out);
}

// Round 7
// 291.700 us; speedup vs baseline: 1.8704x; 1.1066x over previous
//
#include <hip/hip_runtime.h>
#include <hip/hip_bf16.h>

typedef __attribute__((ext_vector_type(8)))  short bf16x8_t;
typedef __attribute__((ext_vector_type(16))) float f32x16_t;
typedef __attribute__((ext_vector_type(4)))  float f32x4_t;

#define HN 10
#define BN 32768
#define DH 256
#define MT 128

#define HE   65536      // elems per (arr,head) weight matrix
#define ARRE 655360     // elems per layer-array (10 heads)

// LDS: abuf 64KB + s5 1KB + bias 4KB
#define OFF_ABUF  0
#define OFF_S5    65536
#define OFF_BIAS  66560
#define SMEM_BYTES 70656

#define MFMA32 __builtin_amdgcn_mfma_f32_32x32x16_bf16

__device__ __forceinline__ unsigned swzoff(int row, int colb) {
  // [128][256] bf16 row-major, 512B/row; XOR row bits into byte bits 4-7
  return (unsigned)(row * 512 + (colb ^ ((row & 15) << 4)));
}

__device__ __forceinline__ unsigned short f2bf(float v) {
  __hip_bfloat16 hb = __float2bfloat16(v);
  return *reinterpret_cast<unsigned short*>(&hb);
}

// ---------------- prep kernels (layouts verified R1-R6) ----------------
struct WPtrs { const float* w[5]; };

extern "C" __global__ void pack_big(WPtrs p, unsigned short* __restrict__ dst)
{
  int g = blockIdx.x * blockDim.x + threadIdx.x;  // 409600
  if (g >= 5 * HN * 16 * 8 * 64) return;
  int lane = g & 63; int t = g >> 6;
  int nt = t & 7; t >>= 3;
  int ks = t & 15; t >>= 4;
  int h = t % HN;
  int a = t / HN;
  const float* src = p.w[a] + (size_t)h * 65536
                   + (nt * 32 + (lane & 31)) * 256 + ks * 16 + (lane >> 5) * 8;
  unsigned short* d = dst + (size_t)a * ARRE + (size_t)h * HE
                    + ((ks * 8 + nt) * 64 + lane) * 8;
  #pragma unroll
  for (int j = 0; j < 8; ++j) d[j] = f2bf(src[j]);
}

extern "C" __global__ void pack_w5(const float* __restrict__ w51, const float* __restrict__ w52,
                                   unsigned short* __restrict__ dst)
{
  int g = blockIdx.x * blockDim.x + threadIdx.x;  // 20480
  if (g >= 2 * HN * 16 * 64) return;
  int lane = g & 63; int t = g >> 6;
  int ks = t & 15; t >>= 4;
  int h = t % HN;
  int br = t / HN;
  const float* w = br ? w52 : w51;   // (10,2,256)
  int col = lane & 31;
  int k = ks * 16 + (lane >> 5) * 8;
  unsigned short* d = dst + ((size_t)(br * HN + h) * 16 + ks) * 512 + lane * 8;
  #pragma unroll
  for (int j = 0; j < 8; ++j) {
    float v = (col < 2) ? w[(size_t)h * 512 + col * 256 + k + j] : 0.f;
    d[j] = f2bf(v);
  }
}

// W1 (10,256,4) -> padded K=16 b-frags: [h][ntile(8)][lane(64)][8]
extern "C" __global__ void pack_w1(const float* __restrict__ w1, unsigned short* __restrict__ dst)
{
  int g = blockIdx.x * blockDim.x + threadIdx.x;  // 5120
  if (g >= HN * 8 * 64) return;
  int lane = g & 63; int t = g >> 6;
  int nt = t & 7;
  int h = t >> 3;
  int col = nt * 32 + (lane & 31);
  unsigned short* d = dst + (size_t)h * 4096 + ((size_t)nt * 64 + lane) * 8;
  #pragma unroll
  for (int j = 0; j < 8; ++j) {
    int k = (lane >> 5) * 8 + j;
    float v = (k < 4) ? w1[(size_t)h * 1024 + col * 4 + k] : 0.f;
    d[j] = f2bf(v);
  }
}

// ---------------- main kernel ----------------
// 256-thread blocks, 4 waves: wm = wave>>1 (row half), wn = wave&1 (col half).
// Wave tile 64 rows x 128 cols, C computed TRANSPOSED in regs (mfma(W, act)):
// lane&31 = activation row, regs = output cols -> 4 consecutive cols pack into
// one ds_write_b64 (16 stores/layer/wave instead of 64 scalar b16 stores).

// C^T write: bias added here, relu, packed b64 stores into swizzled abuf
__device__ __forceinline__ void write_actT(char* abuf, const f32x16_t acc[2][4],
                                           const float* __restrict__ bls,
                                           int lane, int wm, int wn)
{
  const int r31 = lane & 31, hi = lane >> 5;
  #pragma unroll
  for (int mt = 0; mt < 2; ++mt) {
    const int row = wm * 64 + mt * 32 + r31;
    #pragma unroll
    for (int nt = 0; nt < 4; ++nt) {
      #pragma unroll
      for (int g = 0; g < 4; ++g) {
        const int col0 = wn * 128 + nt * 32 + 8 * g + 4 * hi;
        unsigned long long pk = 0;
        #pragma unroll
        for (int j = 0; j < 4; ++j) {
          float v = fmaxf(acc[mt][nt][4 * g + j] + bls[col0 + j], 0.f);
          pk |= (unsigned long long)f2bf(v) << (16 * j);
        }
        *(unsigned long long*)(abuf + swzoff(row, col0 * 2)) = pk;
      }
    }
  }
}

// In-place 128x256 @ 256x256 GEMM. B (weights) streamed from L2 with depth-2
// rotation as MFMA *A*-operand; activations from LDS as *B*-operand.
__device__ __forceinline__ void gemm_ip(char* abuf,
                                        const unsigned short* __restrict__ wl,
                                        const float* __restrict__ bls,
                                        int lane, int wm, int wn)
{
  const int r31 = lane & 31, hi = lane >> 5;
  f32x16_t acc[2][4];
  #pragma unroll
  for (int mt = 0; mt < 2; ++mt)
    #pragma unroll
    for (int nt = 0; nt < 4; ++nt)
      #pragma unroll
      for (int i = 0; i < 16; ++i) acc[mt][nt][i] = 0.f;

  // frag(ks, coltile c) at byte ((ks*8 + c)*64 + lane)*16 ; c = wn*4+nt
  const char* wb = (const char*)wl + (size_t)(wn * 4) * 1024 + (size_t)lane * 16;
  bf16x8_t w0[4], w1r[4], w2[4];
  #pragma unroll
  for (int nt = 0; nt < 4; ++nt) {
    w0[nt]  = *(const bf16x8_t*)(wb + nt * 1024);
    w1r[nt] = *(const bf16x8_t*)(wb + 8192 + nt * 1024);
  }
  #pragma unroll
  for (int ks = 0; ks < 16; ++ks) {
    if (ks < 14) {
      #pragma unroll
      for (int nt = 0; nt < 4; ++nt)
        w2[nt] = *(const bf16x8_t*)(wb + (ks + 2) * 8192 + nt * 1024);
    }
    bf16x8_t a0 = *(const bf16x8_t*)(abuf + swzoff(wm * 64 + r31,      ks * 32 + hi * 16));
    bf16x8_t a1 = *(const bf16x8_t*)(abuf + swzoff(wm * 64 + 32 + r31, ks * 32 + hi * 16));
    #pragma unroll
    for (int nt = 0; nt < 4; ++nt) {
      acc[0][nt] = MFMA32(w0[nt], a0, acc[0][nt], 0, 0, 0);
      acc[1][nt] = MFMA32(w0[nt], a1, acc[1][nt], 0, 0, 0);
    }
    #pragma unroll
    for (int nt = 0; nt < 4; ++nt) { w0[nt] = w1r[nt]; w1r[nt] = w2[nt]; }
  }
  __syncthreads();   // all A-reads landed in acc -> in-place overwrite safe
  write_actT(abuf, acc, bls, lane, wm, wn);
  __syncthreads();
}

extern "C" __global__ __launch_bounds__(256, 2)
void abnet_main(const float* __restrict__ x,
                const float* __restrict__ b1,
                const float* __restrict__ b2, const float* __restrict__ b31,
                const float* __restrict__ b32, const float* __restrict__ b41,
                const float* __restrict__ b42, const float* __restrict__ b51,
                const float* __restrict__ b52,
                const unsigned short* __restrict__ wpk,
                const unsigned short* __restrict__ w5pk,
                const unsigned short* __restrict__ w1pk,
                float* __restrict__ ws51, float* __restrict__ ws52)
{
  extern __shared__ char smem[];
  char*  abuf = smem + OFF_ABUF;
  float* s5   = (float*)(smem + OFF_S5);
  float* bls  = (float*)(smem + OFF_BIAS);   // [4][256]: b1,b2,b3,b4

  const int tid  = threadIdx.x;
  const int lane = tid & 63, wave = tid >> 6;
  const int wm = wave >> 1, wn = wave & 1;
  // XCD-chunked swizzle: 640 consecutive logical blocks per XCD
  const int L  = (blockIdx.x & 7) * 640 + (blockIdx.x >> 3);
  const int rt = L & 255;
  const int hb = L >> 8;                 // 0..19
  const int h  = hb >> 1, br = hb & 1;
  const int row0 = rt * MT;

  const int r31 = lane & 31, hi = lane >> 5;

  // ---- stage biases to LDS (once per block) ----
  for (int i = tid; i < 1024; i += 256) {
    int a = i >> 8, c = i & 255;
    const float* bp = (a == 0) ? b1 : (a == 1) ? b2
                    : (a == 2) ? (br ? b32 : b31) : (br ? b42 : b41);
    bls[i] = bp[(size_t)h * 256 + c];
  }
  __syncthreads();

  // ---- layer 1 via padded-K MFMA (K=4 padded to 16), C^T ----
  {
    const char* w1b = (const char*)(w1pk + (size_t)h * 4096)
                    + (size_t)(wn * 4) * 1024 + (size_t)lane * 16;
    bf16x8_t wf[4];
    #pragma unroll
    for (int nt = 0; nt < 4; ++nt) wf[nt] = *(const bf16x8_t*)(w1b + nt * 1024);
    f32x16_t acc[2][4];
    #pragma unroll
    for (int mt = 0; mt < 2; ++mt)
      #pragma unroll
      for (int nt = 0; nt < 4; ++nt)
        #pragma unroll
        for (int i = 0; i < 16; ++i) acc[mt][nt][i] = 0.f;
    #pragma unroll
    for (int mt = 0; mt < 2; ++mt) {
      int row = row0 + wm * 64 + mt * 32 + r31;
      f32x4_t xv = *(const f32x4_t*)(x + (size_t)row * 4);
      bf16x8_t af;
      #pragma unroll
      for (int j = 0; j < 8; ++j)
        af[j] = (hi == 0 && j < 4) ? (short)f2bf(xv[j]) : (short)0;
      #pragma unroll
      for (int nt = 0; nt < 4; ++nt)
        acc[mt][nt] = MFMA32(wf[nt], af, acc[mt][nt], 0, 0, 0);
    }
    write_actT(abuf, acc, bls, lane, wm, wn);   // + b1, relu
    __syncthreads();
  }

  // ---- three 256x256 layers, in place ----
  gemm_ip(abuf, wpk + (size_t)h * HE,                           bls + 256, lane, wm, wn); // x2
  gemm_ip(abuf, wpk + (size_t)(1 + br) * ARRE + (size_t)h * HE, bls + 512, lane, wm, wn); // x3b
  gemm_ip(abuf, wpk + (size_t)(3 + br) * ARRE + (size_t)h * HE, bls + 768, lane, wm, wn); // x4b

  // ---- final 256->2: each wave takes a 32-row m-tile, full K ----
  {
    const unsigned short* w5 = w5pk + (size_t)(br * HN + h) * 8192;
    const float* b5g = (br ? b52 : b51) + (size_t)h * 2;
    const int mt = wave;
    float bv = (r31 < 2) ? b5g[r31] : 0.f;
    f32x16_t acc;
    #pragma unroll
    for (int i = 0; i < 16; ++i) acc[i] = bv;
    #pragma unroll
    for (int ks = 0; ks < 16; ++ks) {
      bf16x8_t a = *(const bf16x8_t*)(abuf + swzoff(mt * 32 + r31, ks * 32 + hi * 16));
      bf16x8_t b = *(const bf16x8_t*)(w5 + (size_t)(ks * 64 + lane) * 8);
      acc = MFMA32(a, b, acc, 0, 0, 0);
    }
    if (r31 < 2) {
      #pragma unroll
      for (int r = 0; r < 16; ++r) {
        int row = mt * 32 + (r & 3) + 8 * (r >> 2) + 4 * hi;
        s5[row * 2 + r31] = acc[r];
      }
    }
  }
  __syncthreads();

  // ---- write raw final outputs (activation applied in epilogue) ----
  if (tid < 256) {
    int row = tid >> 1, c = tid & 1;
    float* wsout = br ? ws52 : ws51;
    wsout[((size_t)h * BN + row0 + row) * 2 + c] = s5[row * 2 + c];
  }
}

// ---------------- epilogue: CBF + softmax-weighted head combine ----------------
extern "C" __global__ __launch_bounds__(256)
void abnet_epi(const float* __restrict__ x, const float* __restrict__ wt,
               const float* __restrict__ mean, const float* __restrict__ stdv,
               const float* __restrict__ mlab, const float* __restrict__ slab,
               const float* __restrict__ ws51, const float* __restrict__ ws52,
               float* __restrict__ out)
{
  const int row = blockIdx.x * 256 + threadIdx.x;
  f32x4_t xr = *(const f32x4_t*)(x + (size_t)row * 4);
  float t1  = xr[0] * stdv[0] + mean[0];
  float w1v = xr[1] * stdv[1] + mean[1];
  float t2  = xr[2] * stdv[2] + mean[2];
  float w2v = xr[3] * stdv[3] + mean[3];
  float s1, c1, s2, c2;
  sincosf(t1, &s1, &c1);
  sincosf(t2, &s2, &c2);
  float px = 3.f * c1 + 3.f * c2;                // OBS_X = 0
  float py = 3.f * s1 + 3.f * s2 - 7.f;          // OBS_Y = 7
  float vx = -3.f * s1 * w1v - 3.f * s2 * w2v;
  float vy =  3.f * c1 * w1v + 3.f * c2 * w2v;
  float e_bar  = px * px + py * py - 16.f;       // R^2
  float e_bdot = 2.f * (px * vx + py * vy);
  float e_lf2b = 2.f * vx * vx + 2.f * vy * vy
               + 2.f * px * (-3.f * c1 * w1v * w1v - 3.f * c2 * w2v * w2v)
               + 2.f * py * (-3.f * s1 * w1v * w1v - 3.f * s2 * w2v * w2v);
  float e_g1 = 6.f * (px * s1 - py * c1);
  float e_g2 = 6.f * (px * s2 - py * c2);
  float e_ggi = 1.f / (e_g1 * e_g1 + e_g2 * e_g2);

  float m = wt[0];
  for (int i = 1; i < HN; ++i) m = fmaxf(m, wt[i]);
  float s = 0.f;
  for (int i = 0; i < HN; ++i) s += __expf(wt[i] - m);
  float sm_inv = 1.f / s;
  float ml0 = mlab[0], ml1 = mlab[1];
  float isl0 = 1.f / slab[0], isl1 = 1.f / slab[1];

  float a0r = 4.f / (1.f + __expf(-ws52[(size_t)row * 2 + 0]));   // head 0, col 0
  float accu0 = 0.f, accu1 = 0.f;
  for (int h = 0; h < HN; ++h) {
    float u1 = -ws51[((size_t)h * BN + row) * 2 + 0];
    float u2 = -ws51[((size_t)h * BN + row) * 2 + 1];
    float bi = 4.f / (1.f + __expf(-ws52[((size_t)h * BN + row) * 2 + 1]));
    float hv   = e_lf2b + (a0r + bi) * e_bdot + a0r * bi * e_bar;
    float viol = u1 * e_g1 + u2 * e_g2 - hv;
    float lam  = fmaxf(viol, 0.f) * e_ggi;
    float uu1 = u1 - lam * e_g1;
    float uu2 = u2 - lam * e_g2;
    float whv = __expf(wt[h] - m) * sm_inv;
    accu0 += whv * (uu1 - ml0) * isl0;
    accu1 += whv * (uu2 - ml1) * isl1;
  }
  float2 o; o.x = accu0; o.y = accu1;
  *(float2*)(out + (size_t)row * 2) = o;
}

// ---------------- launch ----------------
extern "C" void kernel_launch(void* const* d_in, const int* in_sizes, int n_in,
                              void* d_out, int out_size, void* d_ws, size_t ws_size,
                              hipStream_t stream)
{
  const float* x    = (const float*)d_in[0];
  const float* wt   = (const float*)d_in[2];
  const float* mean = (const float*)d_in[3];
  const float* stdv = (const float*)d_in[4];
  const float* mlab = (const float*)d_in[5];
  const float* slab = (const float*)d_in[6];
  const float* W1   = (const float*)d_in[7];
  const float* b1   = (const float*)d_in[8];
  WPtrs wp;
  wp.w[0] = (const float*)d_in[9];   // W2
  wp.w[1] = (const float*)d_in[11];  // W31
  wp.w[2] = (const float*)d_in[13];  // W32
  wp.w[3] = (const float*)d_in[15];  // W41
  wp.w[4] = (const float*)d_in[17];  // W42
  const float* b2  = (const float*)d_in[10];
  const float* b31 = (const float*)d_in[12];
  const float* b32 = (const float*)d_in[14];
  const float* b41 = (const float*)d_in[16];
  const float* b42 = (const float*)d_in[18];
  const float* W51 = (const float*)d_in[19];
  const float* b51 = (const float*)d_in[20];
  const float* W52 = (const float*)d_in[21];
  const float* b52 = (const float*)d_in[22];

  char* wsb = (char*)d_ws;
  unsigned short* wpk  = (unsigned short*)wsb;                       // 6,553,600 B
  unsigned short* w5pk = (unsigned short*)(wsb + 6553600);           //   327,680 B
  unsigned short* w1pk = (unsigned short*)(wsb + 6881280);           //    81,920 B
  float* ws51 = (float*)(wsb + 6963200);                             // 2,621,440 B
  float* ws52 = (float*)(wsb + 9584640);                             // 2,621,440 B

  hipLaunchKernelGGL(pack_big, dim3(1600), dim3(256), 0, stream, wp, wpk);
  hipLaunchKernelGGL(pack_w5,  dim3(80),   dim3(256), 0, stream, W51, W52, w5pk);
  hipLaunchKernelGGL(pack_w1,  dim3(20),   dim3(256), 0, stream, W1, w1pk);

  (void)hipFuncSetAttribute(reinterpret_cast<const void*>(abnet_main),
                            hipFuncAttributeMaxDynamicSharedMemorySize, SMEM_BYTES);
  hipLaunchKernelGGL(abnet_main, dim3(256 * HN * 2), dim3(256), SMEM_BYTES, stream,
                     x, b1, b2, b31, b32, b41, b42, b51, b52,
                     wpk, w5pk, w1pk, ws51, ws52);
  hipLaunchKernelGGL(abnet_epi, dim3(BN / 256), dim3(256), 0, stream,
                     x, wt, mean, stdv, mlab, slab, ws51, ws52, (float*)d_out);
}

// Round 8
// 277.167 us; speedup vs baseline: 1.9685x; 1.0524x over previous
//
#include <hip/hip_runtime.h>
#include <hip/hip_bf16.h>

typedef __attribute__((ext_vector_type(8)))  short bf16x8_t;
typedef __attribute__((ext_vector_type(16))) float f32x16_t;
typedef __attribute__((ext_vector_type(4)))  float f32x4_t;

#define HN 10
#define BN 32768
#define DH 256
#define MT 128

// 17 K-steps per layer (17th = bias row, consumed against a ones-frag)
#define KS17 17
#define HE17   (KS17*8*64*8)     // 69632 elems per (arr,head)
#define ARRE17 (HN*HE17)         // 696320

// LDS: abuf 64KB + s5 1KB
#define OFF_ABUF  0
#define OFF_S5    65536
#define SMEM_BYTES 66560

#define MFMA32 __builtin_amdgcn_mfma_f32_32x32x16_bf16

__device__ __forceinline__ unsigned swzoff(int row, int colb) {
  // [128][256] bf16 row-major, 512B/row; XOR row bits 0-4 into byte bits 4-8:
  // 32 16B slots per row-window -> 64-lane access lands 2 lanes/slot (free).
  return (unsigned)(row * 512 + (colb ^ ((row & 31) << 4)));
}

__device__ __forceinline__ unsigned short f2bf(float v) {
  __hip_bfloat16 hb = __float2bfloat16(v);
  return *reinterpret_cast<unsigned short*>(&hb);
}
__device__ __forceinline__ unsigned pk2bf(float lo, float hi_) {
  return (unsigned)f2bf(lo) | ((unsigned)f2bf(hi_) << 16);
}

// ---------------- prep kernels ----------------
struct WPtrs { const float* w[5]; const float* b[5]; };

// [arr][h][ks(17)][nt(8)][lane(64)][8] ; ks==16 carries the bias row (k=256)
extern "C" __global__ void pack_big(WPtrs p, unsigned short* __restrict__ dst)
{
  int g = blockIdx.x * blockDim.x + threadIdx.x;  // 435200
  if (g >= 5 * HN * KS17 * 8 * 64) return;
  int lane = g & 63; int t = g >> 6;
  int nt = t & 7; t >>= 3;
  int ks = t % KS17; t /= KS17;
  int h = t % HN;
  int a = t / HN;
  int col = nt * 32 + (lane & 31);
  int hi = lane >> 5;
  unsigned short* d = dst + (size_t)a * ARRE17 + (size_t)h * HE17
                    + ((ks * 8 + nt) * 64 + lane) * 8;
  if (ks < 16) {
    const float* src = p.w[a] + (size_t)h * 65536 + col * 256 + ks * 16 + hi * 8;
    #pragma unroll
    for (int j = 0; j < 8; ++j) d[j] = f2bf(src[j]);
  } else {
    float bv = p.b[a][(size_t)h * 256 + col];
    #pragma unroll
    for (int j = 0; j < 8; ++j) d[j] = (hi == 0 && j == 0) ? f2bf(bv) : (unsigned short)0;
  }
}

// [br][h][ks(17)][lane(64)][8] ; ks==16 = bias
extern "C" __global__ void pack_w5(const float* __restrict__ w51, const float* __restrict__ w52,
                                   const float* __restrict__ b51, const float* __restrict__ b52,
                                   unsigned short* __restrict__ dst)
{
  int g = blockIdx.x * blockDim.x + threadIdx.x;  // 21760
  if (g >= 2 * HN * KS17 * 64) return;
  int lane = g & 63; int t = g >> 6;
  int ks = t % KS17; t /= KS17;
  int h = t % HN;
  int br = t / HN;
  const float* w = br ? w52 : w51;   // (10,2,256)
  const float* b = br ? b52 : b51;   // (10,2)
  int col = lane & 31;
  int hi = lane >> 5;
  unsigned short* d = dst + ((size_t)(br * HN + h) * KS17 + ks) * 512 + lane * 8;
  if (ks < 16) {
    int k = ks * 16 + hi * 8;
    #pragma unroll
    for (int j = 0; j < 8; ++j) {
      float v = (col < 2) ? w[(size_t)h * 512 + col * 256 + k + j] : 0.f;
      d[j] = f2bf(v);
    }
  } else {
    float bv = (col < 2) ? b[(size_t)h * 2 + col] : 0.f;
    #pragma unroll
    for (int j = 0; j < 8; ++j) d[j] = (hi == 0 && j == 0) ? f2bf(bv) : (unsigned short)0;
  }
}

// W1 (10,256,4)+b1 -> padded K=16 frags: [h][nt(8)][lane(64)][8]; bias at k=4
extern "C" __global__ void pack_w1(const float* __restrict__ w1, const float* __restrict__ b1,
                                   unsigned short* __restrict__ dst)
{
  int g = blockIdx.x * blockDim.x + threadIdx.x;  // 5120
  if (g >= HN * 8 * 64) return;
  int lane = g & 63; int t = g >> 6;
  int nt = t & 7;
  int h = t >> 3;
  int col = nt * 32 + (lane & 31);
  int hi = lane >> 5;
  unsigned short* d = dst + (size_t)h * 4096 + ((size_t)nt * 64 + lane) * 8;
  #pragma unroll
  for (int j = 0; j < 8; ++j) {
    int k = hi * 8 + j;
    float v = 0.f;
    if (k < 4)       v = w1[(size_t)h * 1024 + col * 4 + k];
    else if (k == 4) v = b1[(size_t)h * 256 + col];
    d[j] = f2bf(v);
  }
}

// ---------------- main kernel ----------------
// 256-thread blocks, 4 waves. Wave tile: ALL 128 rows x 64 cols (cols = wave*64).
// C^T in regs: mfma(W_frag as A, act_frag as B) -> lane&31 = batch row,
// regs = out cols. acc[4 mt][2 nt] = 128 regs.

__device__ __forceinline__ void write_actT(char* abuf, const f32x16_t acc[4][2],
                                           int lane, int wave)
{
  const int r31 = lane & 31, hi = lane >> 5;
  #pragma unroll
  for (int mt = 0; mt < 4; ++mt) {
    const int row = mt * 32 + r31;
    #pragma unroll
    for (int nt = 0; nt < 2; ++nt) {
      #pragma unroll
      for (int g = 0; g < 4; ++g) {
        const int col0 = (wave * 2 + nt) * 32 + 8 * g + 4 * hi;
        unsigned w0 = pk2bf(fmaxf(acc[mt][nt][4 * g + 0], 0.f),
                            fmaxf(acc[mt][nt][4 * g + 1], 0.f));
        unsigned w1 = pk2bf(fmaxf(acc[mt][nt][4 * g + 2], 0.f),
                            fmaxf(acc[mt][nt][4 * g + 3], 0.f));
        unsigned long long pk = (unsigned long long)w0 | ((unsigned long long)w1 << 32);
        *(unsigned long long*)(abuf + swzoff(row, col0 * 2)) = pk;
      }
    }
  }
}

// In-place 128x256 @ 256x(256+bias) GEMM, relu. Weights streamed from L2
// (depth-2 rotation); 17th K-step consumes bias row against ones-frag.
__device__ __forceinline__ void gemm_ip(char* abuf,
                                        const unsigned short* __restrict__ wl,
                                        int lane, int wave, bf16x8_t ones)
{
  const int r31 = lane & 31, hi = lane >> 5;
  f32x16_t acc[4][2];
  #pragma unroll
  for (int mt = 0; mt < 4; ++mt)
    #pragma unroll
    for (int nt = 0; nt < 2; ++nt)
      #pragma unroll
      for (int i = 0; i < 16; ++i) acc[mt][nt][i] = 0.f;

  // frag(ks, c=wave*2+nt) at byte ((ks*8 + c)*64 + lane)*16
  const char* wb = (const char*)wl + (size_t)(wave * 2) * 1024 + (size_t)lane * 16;
  bf16x8_t c0[2], c1[2], c2[2];
  #pragma unroll
  for (int nt = 0; nt < 2; ++nt) {
    c0[nt] = *(const bf16x8_t*)(wb + nt * 1024);
    c1[nt] = *(const bf16x8_t*)(wb + 8192 + nt * 1024);
  }
  #pragma unroll
  for (int ks = 0; ks < KS17; ++ks) {
    if (ks < KS17 - 2) {
      #pragma unroll
      for (int nt = 0; nt < 2; ++nt)
        c2[nt] = *(const bf16x8_t*)(wb + (ks + 2) * 8192 + nt * 1024);
    }
    bf16x8_t a[4];
    #pragma unroll
    for (int mt = 0; mt < 4; ++mt)
      a[mt] = (ks < 16)
        ? *(const bf16x8_t*)(abuf + swzoff(mt * 32 + r31, ks * 32 + hi * 16))
        : ones;
    #pragma unroll
    for (int mt = 0; mt < 4; ++mt) {
      acc[mt][0] = MFMA32(c0[0], a[mt], acc[mt][0], 0, 0, 0);
      acc[mt][1] = MFMA32(c0[1], a[mt], acc[mt][1], 0, 0, 0);
    }
    #pragma unroll
    for (int nt = 0; nt < 2; ++nt) { c0[nt] = c1[nt]; c1[nt] = c2[nt]; }
  }
  __syncthreads();   // all act reads landed in acc -> in-place overwrite safe
  write_actT(abuf, acc, lane, wave);
  __syncthreads();
}

extern "C" __global__ __launch_bounds__(256, 2)
void abnet_main(const float* __restrict__ x,
                const unsigned short* __restrict__ wpk,
                const unsigned short* __restrict__ w5pk,
                const unsigned short* __restrict__ w1pk,
                float* __restrict__ ws51, float* __restrict__ ws52)
{
  extern __shared__ char smem[];
  char*  abuf = smem + OFF_ABUF;
  float* s5   = (float*)(smem + OFF_S5);

  const int tid  = threadIdx.x;
  const int lane = tid & 63, wave = tid >> 6;
  // XCD-chunked swizzle: 640 consecutive logical blocks per XCD
  const int L  = (blockIdx.x & 7) * 640 + (blockIdx.x >> 3);
  const int rt = L & 255;
  const int hb = L >> 8;                 // 0..19
  const int h  = hb >> 1, br = hb & 1;
  const int row0 = rt * MT;

  const int r31 = lane & 31, hi = lane >> 5;

  // ones-frag: B[k][*]=1 at k-slot 0 of hi=0 (k=256 for 17th step; k=4 for L1)
  bf16x8_t ones;
  #pragma unroll
  for (int j = 0; j < 8; ++j) ones[j] = 0;
  if (hi == 0) ones[0] = (short)0x3F80;   // bf16 1.0

  // ---- layer 1 via padded-K MFMA (K=4 + bias at k=4), C^T ----
  {
    const char* w1b = (const char*)(w1pk + (size_t)h * 4096)
                    + (size_t)(wave * 2) * 1024 + (size_t)lane * 16;
    bf16x8_t wf[2];
    #pragma unroll
    for (int nt = 0; nt < 2; ++nt) wf[nt] = *(const bf16x8_t*)(w1b + nt * 1024);
    f32x16_t acc[4][2];
    #pragma unroll
    for (int mt = 0; mt < 4; ++mt)
      #pragma unroll
      for (int nt = 0; nt < 2; ++nt)
        #pragma unroll
        for (int i = 0; i < 16; ++i) acc[mt][nt][i] = 0.f;
    #pragma unroll
    for (int mt = 0; mt < 4; ++mt) {
      int row = row0 + mt * 32 + r31;
      f32x4_t xv = *(const f32x4_t*)(x + (size_t)row * 4);
      bf16x8_t af;
      #pragma unroll
      for (int j = 0; j < 8; ++j) {
        short v = 0;
        if (hi == 0) {
          if (j < 4)       v = (short)f2bf(xv[j]);
          else if (j == 4) v = (short)0x3F80;   // ones slot for bias row
        }
        af[j] = v;
      }
      acc[mt][0] = MFMA32(wf[0], af, acc[mt][0], 0, 0, 0);
      acc[mt][1] = MFMA32(wf[1], af, acc[mt][1], 0, 0, 0);
    }
    write_actT(abuf, acc, lane, wave);   // waves write disjoint cols
    __syncthreads();
  }

  // ---- three 256x256 layers, in place ----
  gemm_ip(abuf, wpk + (size_t)h * HE17,                             lane, wave, ones); // x2
  gemm_ip(abuf, wpk + (size_t)(1 + br) * ARRE17 + (size_t)h * HE17, lane, wave, ones); // x3b
  gemm_ip(abuf, wpk + (size_t)(3 + br) * ARRE17 + (size_t)h * HE17, lane, wave, ones); // x4b

  // ---- final 256->2 (+bias step): wave = 32-row m-tile, full K ----
  {
    const unsigned short* w5 = w5pk + (size_t)(br * HN + h) * (KS17 * 512);
    const int mt = wave;
    f32x16_t acc;
    #pragma unroll
    for (int i = 0; i < 16; ++i) acc[i] = 0.f;
    #pragma unroll
    for (int ks = 0; ks < KS17; ++ks) {
      bf16x8_t a = (ks < 16)
        ? *(const bf16x8_t*)(abuf + swzoff(mt * 32 + r31, ks * 32 + hi * 16))
        : ones;
      bf16x8_t b = *(const bf16x8_t*)(w5 + (size_t)(ks * 64 + lane) * 8);
      acc = MFMA32(a, b, acc, 0, 0, 0);
    }
    if (r31 < 2) {
      #pragma unroll
      for (int r = 0; r < 16; ++r) {
        int row = mt * 32 + (r & 3) + 8 * (r >> 2) + 4 * hi;
        s5[row * 2 + r31] = acc[r];
      }
    }
  }
  __syncthreads();

  // ---- write raw final outputs (activation applied in epilogue) ----
  if (tid < 256) {
    int row = tid >> 1, c = tid & 1;
    float* wsout = br ? ws52 : ws51;
    wsout[((size_t)h * BN + row0 + row) * 2 + c] = s5[row * 2 + c];
  }
}

// ---------------- epilogue: CBF + softmax-weighted head combine ----------------
extern "C" __global__ __launch_bounds__(256)
void abnet_epi(const float* __restrict__ x, const float* __restrict__ wt,
               const float* __restrict__ mean, const float* __restrict__ stdv,
               const float* __restrict__ mlab, const float* __restrict__ slab,
               const float* __restrict__ ws51, const float* __restrict__ ws52,
               float* __restrict__ out)
{
  const int row = blockIdx.x * 256 + threadIdx.x;
  f32x4_t xr = *(const f32x4_t*)(x + (size_t)row * 4);
  float t1  = xr[0] * stdv[0] + mean[0];
  float w1v = xr[1] * stdv[1] + mean[1];
  float t2  = xr[2] * stdv[2] + mean[2];
  float w2v = xr[3] * stdv[3] + mean[3];
  float s1, c1, s2, c2;
  sincosf(t1, &s1, &c1);
  sincosf(t2, &s2, &c2);
  float px = 3.f * c1 + 3.f * c2;                // OBS_X = 0
  float py = 3.f * s1 + 3.f * s2 - 7.f;          // OBS_Y = 7
  float vx = -3.f * s1 * w1v - 3.f * s2 * w2v;
  float vy =  3.f * c1 * w1v + 3.f * c2 * w2v;
  float e_bar  = px * px + py * py - 16.f;       // R^2
  float e_bdot = 2.f * (px * vx + py * vy);
  float e_lf2b = 2.f * vx * vx + 2.f * vy * vy
               + 2.f * px * (-3.f * c1 * w1v * w1v - 3.f * c2 * w2v * w2v)
               + 2.f * py * (-3.f * s1 * w1v * w1v - 3.f * s2 * w2v * w2v);
  float e_g1 = 6.f * (px * s1 - py * c1);
  float e_g2 = 6.f * (px * s2 - py * c2);
  float e_ggi = 1.f / (e_g1 * e_g1 + e_g2 * e_g2);

  float m = wt[0];
  for (int i = 1; i < HN; ++i) m = fmaxf(m, wt[i]);
  float s = 0.f;
  for (int i = 0; i < HN; ++i) s += __expf(wt[i] - m);
  float sm_inv = 1.f / s;
  float ml0 = mlab[0], ml1 = mlab[1];
  float isl0 = 1.f / slab[0], isl1 = 1.f / slab[1];

  float a0r = 4.f / (1.f + __expf(-ws52[(size_t)row * 2 + 0]));   // head 0, col 0
  float accu0 = 0.f, accu1 = 0.f;
  for (int h = 0; h < HN; ++h) {
    float u1 = -ws51[((size_t)h * BN + row) * 2 + 0];
    float u2 = -ws51[((size_t)h * BN + row) * 2 + 1];
    float bi = 4.f / (1.f + __expf(-ws52[((size_t)h * BN + row) * 2 + 1]));
    float hv   = e_lf2b + (a0r + bi) * e_bdot + a0r * bi * e_bar;
    float viol = u1 * e_g1 + u2 * e_g2 - hv;
    float lam  = fmaxf(viol, 0.f) * e_ggi;
    float uu1 = u1 - lam * e_g1;
    float uu2 = u2 - lam * e_g2;
    float whv = __expf(wt[h] - m) * sm_inv;
    accu0 += whv * (uu1 - ml0) * isl0;
    accu1 += whv * (uu2 - ml1) * isl1;
  }
  float2 o; o.x = accu0; o.y = accu1;
  *(float2*)(out + (size_t)row * 2) = o;
}

// ---------------- launch ----------------
extern "C" void kernel_launch(void* const* d_in, const int* in_sizes, int n_in,
                              void* d_out, int out_size, void* d_ws, size_t ws_size,
                              hipStream_t stream)
{
  const float* x    = (const float*)d_in[0];
  const float* wt   = (const float*)d_in[2];
  const float* mean = (const float*)d_in[3];
  const float* stdv = (const float*)d_in[4];
  const float* mlab = (const float*)d_in[5];
  const float* slab = (const float*)d_in[6];
  const float* W1   = (const float*)d_in[7];
  const float* b1   = (const float*)d_in[8];
  WPtrs wp;
  wp.w[0] = (const float*)d_in[9];   // W2
  wp.w[1] = (const float*)d_in[11];  // W31
  wp.w[2] = (const float*)d_in[13];  // W32
  wp.w[3] = (const float*)d_in[15];  // W41
  wp.w[4] = (const float*)d_in[17];  // W42
  wp.b[0] = (const float*)d_in[10];  // b2
  wp.b[1] = (const float*)d_in[12];  // b31
  wp.b[2] = (const float*)d_in[14];  // b32
  wp.b[3] = (const float*)d_in[16];  // b41
  wp.b[4] = (const float*)d_in[18];  // b42
  const float* W51 = (const float*)d_in[19];
  const float* b51 = (const float*)d_in[20];
  const float* W52 = (const float*)d_in[21];
  const float* b52 = (const float*)d_in[22];

  char* wsb = (char*)d_ws;
  unsigned short* wpk  = (unsigned short*)wsb;                       // 6,963,200 B
  unsigned short* w5pk = (unsigned short*)(wsb + 6963200);           //   348,160 B
  unsigned short* w1pk = (unsigned short*)(wsb + 7311360);           //    81,920 B
  float* ws51 = (float*)(wsb + 7393280);                             // 2,621,440 B
  float* ws52 = (float*)(wsb + 10014720);                            // 2,621,440 B

  hipLaunchKernelGGL(pack_big, dim3(1700), dim3(256), 0, stream, wp, wpk);
  hipLaunchKernelGGL(pack_w5,  dim3(85),   dim3(256), 0, stream, W51, W52, b51, b52, w5pk);
  hipLaunchKernelGGL(pack_w1,  dim3(20),   dim3(256), 0, stream, W1, b1, w1pk);

  (void)hipFuncSetAttribute(reinterpret_cast<const void*>(abnet_main),
                            hipFuncAttributeMaxDynamicSharedMemorySize, SMEM_BYTES);
  hipLaunchKernelGGL(abnet_main, dim3(256 * HN * 2), dim3(256), SMEM_BYTES, stream,
                     x, wpk, w5pk, w1pk, ws51, ws52);
  hipLaunchKernelGGL(abnet_epi, dim3(BN / 256), dim3(256), 0, stream,
                     x, wt, mean, stdv, mlab, slab, ws51, ws52, (float*)d_out);
}